// Round 1
// baseline (123.651 us; speedup 1.0000x reference)
//
#include <hip/hip_runtime.h>
#include <hip/hip_bf16.h>

#define CROP_H 14
#define CROP_W 14
#define FM_N 4
#define FM_C 256
#define FM_H 200
#define FM_W 200

__global__ __launch_bounds__(256) void roi_align_kernel(
    const float* __restrict__ fm,      // (N, C, H, W)
    const float* __restrict__ boxes,   // (M, 4) x1,y1,x2,y2
    const int*   __restrict__ box_ind, // (M,)
    float* __restrict__ out,           // (M, C, 14, 14)
    int total)
{
    int idx = blockIdx.x * blockDim.x + threadIdx.x;
    if (idx >= total) return;

    const int HW = CROP_H * CROP_W;           // 196
    int ij = idx % HW;
    int mc = idx / HW;
    int c  = mc % FM_C;
    int m  = mc / FM_C;
    int i  = ij / CROP_W;
    int j  = ij % CROP_W;

    // Box parameters (broadcast across 196*256 threads -> cache hits)
    float x1 = boxes[4 * m + 0];
    float y1 = boxes[4 * m + 1];
    float x2 = boxes[4 * m + 2];
    float y2 = boxes[4 * m + 3];
    int   b  = box_ind[m];

    const float Wm1 = (float)(FM_W - 1);   // 199
    const float Hm1 = (float)(FM_H - 1);   // 199

    float spacing_w = (x2 - x1) / (float)CROP_W;
    float spacing_h = (y2 - y1) / (float)CROP_H;

    float nx0 = (x1 + spacing_w * 0.5f - 0.5f) / Wm1;
    float ny0 = (y1 + spacing_h * 0.5f - 0.5f) / Hm1;
    float nw  = spacing_w * (float)(CROP_W - 1) / Wm1;
    float nh  = spacing_h * (float)(CROP_H - 1) / Hm1;

    // linspace(0,1,14): step = 1/13
    float gy = (float)i * (1.0f / 13.0f);
    float gx = (float)j * (1.0f / 13.0f);

    float sy = ny0 + nh * gy;
    float sx = nx0 + nw * gx;
    float py = sy * Hm1;
    float px = sx * Wm1;

    float y0f = floorf(py);
    float x0f = floorf(px);
    float wy = py - y0f;
    float wx = px - x0f;
    int y0 = (int)y0f;
    int x0 = (int)x0f;
    int y1i = y0 + 1;
    int x1i = x0 + 1;

    float v00ok = (y0  >= 0 && y0  < FM_H && x0  >= 0 && x0  < FM_W) ? 1.0f : 0.0f;
    float v01ok = (y0  >= 0 && y0  < FM_H && x1i >= 0 && x1i < FM_W) ? 1.0f : 0.0f;
    float v10ok = (y1i >= 0 && y1i < FM_H && x0  >= 0 && x0  < FM_W) ? 1.0f : 0.0f;
    float v11ok = (y1i >= 0 && y1i < FM_H && x1i >= 0 && x1i < FM_W) ? 1.0f : 0.0f;

    float w00 = (1.0f - wy) * (1.0f - wx) * v00ok;
    float w01 = (1.0f - wy) * wx          * v01ok;
    float w10 = wy          * (1.0f - wx) * v10ok;
    float w11 = wy          * wx          * v11ok;

    int y0c = min(max(y0,  0), FM_H - 1);
    int y1c = min(max(y1i, 0), FM_H - 1);
    int x0c = min(max(x0,  0), FM_W - 1);
    int x1c = min(max(x1i, 0), FM_W - 1);

    // base plane for (b, c)
    const float* plane = fm + ((size_t)b * FM_C + (size_t)c) * (FM_H * FM_W);

    float v00 = plane[y0c * FM_W + x0c];
    float v01 = plane[y0c * FM_W + x1c];
    float v10 = plane[y1c * FM_W + x0c];
    float v11 = plane[y1c * FM_W + x1c];

    float r = v00 * w00 + v01 * w01 + v10 * w10 + v11 * w11;

    out[idx] = r;
}

extern "C" void kernel_launch(void* const* d_in, const int* in_sizes, int n_in,
                              void* d_out, int out_size, void* d_ws, size_t ws_size,
                              hipStream_t stream) {
    const float* fm      = (const float*)d_in[0];
    const float* boxes   = (const float*)d_in[1];
    const int*   box_ind = (const int*)d_in[2];
    float* out = (float*)d_out;

    int total = out_size; // M * C * 14 * 14
    int block = 256;
    int grid = (total + block - 1) / block;
    roi_align_kernel<<<grid, block, 0, stream>>>(fm, boxes, box_ind, out, total);
}